// Round 6
// baseline (6021.159 us; speedup 1.0000x reference)
//
#include <hip/hip_runtime.h>
#include <math.h>

#define N_ROWS 10816   // 64 * 169 rows per timestep
#define T_SEQ 55
#define NPIX 169

__device__ __forceinline__ float sigmoidf_(float x){ return 1.0f/(1.0f+expf(-x)); }

// ---------------------------------------------------------------------------
// Kernel 1: fused input transpose + 4x (1x1 conv + ReLU) chain. (unchanged)
// ---------------------------------------------------------------------------
__global__ __launch_bounds__(256) void conv1x1_chain(
    const float* __restrict__ x,
    const float* __restrict__ w0, const float* __restrict__ b0,
    const float* __restrict__ w1, const float* __restrict__ b1,
    const float* __restrict__ w2, const float* __restrict__ b2,
    const float* __restrict__ w3, const float* __restrict__ b3,
    float* __restrict__ out)
{
    int n = blockIdx.x*256 + threadIdx.x;
    int l = blockIdx.y;
    if (n >= N_ROWS) return;
    const float* xp = x + ((size_t)n*T_SEQ + l)*24;
    float in24[24];
    #pragma unroll
    for (int i=0;i<6;i++){
        float4 v = *(const float4*)(xp + 4*i);
        in24[4*i]=v.x; in24[4*i+1]=v.y; in24[4*i+2]=v.z; in24[4*i+3]=v.w;
    }
    float a[30], c[30];
    #pragma unroll
    for (int co=0;co<30;co++) a[co]=b0[co];
    #pragma unroll
    for (int ci=0;ci<24;ci++){
        float v = in24[ci];
        #pragma unroll
        for (int co=0;co<30;co++) a[co] = fmaf(v, w0[ci*30+co], a[co]);
    }
    #pragma unroll
    for (int co=0;co<30;co++) a[co] = fmaxf(a[co],0.f);

#define LAYER30(wp, bp) \
    { _Pragma("unroll") for (int co=0;co<30;co++) c[co]=(bp)[co]; \
      _Pragma("unroll") for (int ci=0;ci<30;ci++){ float v=a[ci]; \
        _Pragma("unroll") for (int co=0;co<30;co++) c[co]=fmaf(v,(wp)[ci*30+co],c[co]); } \
      _Pragma("unroll") for (int co=0;co<30;co++) a[co]=fmaxf(c[co],0.f); }

    LAYER30(w1,b1);
    LAYER30(w2,b2);
    LAYER30(w3,b3);
#undef LAYER30

    float* op = out + (size_t)l*30*N_ROWS + n;
    #pragma unroll
    for (int co=0;co<30;co++) op[(size_t)co*N_ROWS] = a[co];
}

// ---------------------------------------------------------------------------
// Kernel 2: 5x5 SAME conv + ReLU, channel-major, IN-PLACE, TWO-PHASE staging.
// (unchanged from R3)
// ---------------------------------------------------------------------------
__global__ __launch_bounds__(192) void conv5x5(
    float* __restrict__ buf, const float* __restrict__ w,
    const float* __restrict__ bias)
{
    __shared__ float img[15*289];
    int bi = blockIdx.x;
    int l = bi >> 6;
    int b = bi & 63;
    float* ip = buf + (size_t)l*30*N_ROWS + (size_t)b*NPIX;
    int tid = threadIdx.x;

    int p = tid;
    bool act = p < 169;
    int pc = act ? p : 0;
    int y = pc/13, x0 = pc - y*13;

    float acc[30];
    #pragma unroll
    for (int co=0;co<30;co++) acc[co]=bias[co];

    for (int i = tid; i < 15*289; i += 192) img[i] = 0.f;

    for (int half = 0; half < 2; half++){
        __syncthreads();
        for (int i = tid; i < 15*169; i += 192){
            int ci = i/169, pp = i - ci*169;
            int yy = pp/13, xx = pp - yy*13;
            img[ci*289 + (yy+2)*17 + (xx+2)] =
                ip[(size_t)(half*15 + ci)*N_ROWS + pp];
        }
        __syncthreads();
        for (int dy=0; dy<5; dy++){
          for (int dx=0; dx<5; dx++){
            const float* wp = w + (size_t)((dy*5+dx)*30 + half*15)*30;
            const float* im = img + (y+dy)*17 + (x0+dx);
            #pragma unroll
            for (int ci=0; ci<15; ci++){
              float v = im[ci*289];
              #pragma unroll
              for (int co=0;co<30;co++) acc[co] = fmaf(v, wp[ci*30+co], acc[co]);
            }
          }
        }
    }
    if (act){
      #pragma unroll
      for (int co=0;co<30;co++) ip[(size_t)co*N_ROWS + p] = fmaxf(acc[co],0.f);
    }
}

// ---------------------------------------------------------------------------
// Kernel 3: weight repack. pc = c*4 + g (c zero-padded to 128), [k][512].
// (unchanged from R5: coalesced 512 B/wave weight stream)
// ---------------------------------------------------------------------------
__global__ __launch_bounds__(256) void repack_w2(
    const float* __restrict__ l1w, const float* __restrict__ l1b,
    const float* __restrict__ l2w, const float* __restrict__ l2b,
    float* __restrict__ pw1, float* __restrict__ pb1,
    float* __restrict__ pw2, float* __restrict__ pb2)
{
    const int T1 = 130*512, T2 = 200*512;
    int i = blockIdx.x*256 + threadIdx.x;
    if (i < T1){
        int k = i >> 9, pc = i & 511, c = pc >> 2, g = pc & 3;
        pw1[i] = (c < 100) ? l1w[(size_t)k*400 + g*100 + c] : 0.f;
    } else if (i < T1 + T2){
        int ii = i - T1;
        int k = ii >> 9, pc = ii & 511, c = pc >> 2, g = pc & 3;
        pw2[ii] = (c < 100) ? l2w[(size_t)k*400 + g*100 + c] : 0.f;
    } else if (i < T1 + T2 + 512){
        int pc = i - T1 - T2, c = pc >> 2, g = pc & 3;
        pb1[pc] = (c < 100) ? l1b[g*100 + c] : 0.f;
    } else if (i < T1 + T2 + 1024){
        int pc = i - T1 - T2 - 512, c = pc >> 2, g = pc & 3;
        pb2[pc] = (c < 100) ? l2b[g*100 + c] : 0.f;
    }
}

// ---------------------------------------------------------------------------
// Kernel 4: PERSISTENT fused 2-layer LSTM + projection, v3: 8 rows/block.
// Grid 1352 blocks (5.28/CU) x 4 waves = ~21 waves/CU — fixes R5's
// grid-limited 2.64 waves/SIMD latency exposure. Per k per wave: one
// coalesced float2 weight load (L2) + 2 broadcast ds_read_b128 + 16 FMA.
// LDS 14.2 KB/block. Lane = 2 packed cols x 8 rows = 16 accs.
// ---------------------------------------------------------------------------
__global__ __launch_bounds__(256) void lstm_persist3(
    const float* __restrict__ xall,   // [55][30][N]
    const float* __restrict__ pw1, const float* __restrict__ pb1,
    const float* __restrict__ pw2, const float* __restrict__ pb2,
    const float* __restrict__ we,  const float* __restrict__ be,
    float* __restrict__ out)          // [N][55]
{
    __shared__ float xs[30*8];        // [k][r]
    __shared__ float h1[2][100*8];    // [c][r] double buffer
    __shared__ float h2[2][100*8];
    __shared__ float pbuf[64];

    const int tid  = threadIdx.x;
    const int wave = tid >> 6;
    const int lane = tid & 63;
    const int n0   = blockIdx.x * 8;
    const int pc0  = wave*128 + lane*2;   // my 2 packed cols
    const int c    = pc0 >> 2;            // my cell index (0..127)
    const int codd = lane & 1;            // 0: gates (i,j); 1: gates (f,o)
    const bool cvalid = (c < 100);

    for (int i=tid; i<800; i+=256){ h1[0][i]=0.f; h2[0][i]=0.f; }

    float cs1[8], cs2[8];
    #pragma unroll
    for (int r=0;r<8;r++){ cs1[r]=0.f; cs2[r]=0.f; }

    const float2 b1v = *(const float2*)(pb1 + pc0);
    const float2 b2v = *(const float2*)(pb2 + pc0);

    __syncthreads();

    float accA[8], accB[8], hreg[8];

#define GK(PW, ACT, KBASE, KLEN) \
    { _Pragma("unroll 2") \
      for (int k=0; k<(KLEN); k++){ \
        float2 wv = *(const float2*)((PW) + (size_t)((KBASE)+k)*512 + pc0); \
        const float4* ap = (const float4*)((ACT) + k*8); \
        float av[8]; \
        *(float4*)(av+0)=ap[0]; *(float4*)(av+4)=ap[1]; \
        _Pragma("unroll") \
        for (int r=0;r<8;r++){ \
            accA[r]=fmaf(av[r],wv.x,accA[r]); \
            accB[r]=fmaf(av[r],wv.y,accB[r]); } } }

#define EPI(CS, HDST) \
    { _Pragma("unroll") \
      for (int r=0;r<8;r++){ \
        float za = accA[r], zb = accB[r]; \
        float oa = __shfl_xor(za, 1, 64); \
        float ob = __shfl_xor(zb, 1, 64); \
        float zi = codd ? oa : za; \
        float zj = codd ? ob : zb; \
        float zf = codd ? za : oa; \
        float zo = codd ? zb : ob; \
        float gi = sigmoidf_(zi); \
        float gj = tanhf(zj); \
        float gf = sigmoidf_(zf + 1.0f); \
        float go = sigmoidf_(zo); \
        float cn = gf*(CS)[r] + gi*gj; \
        (CS)[r] = cn; \
        hreg[r] = go * tanhf(cn); } \
      if (cvalid && !codd){ \
        float4* hp = (float4*)((HDST) + c*8); \
        hp[0] = *(float4*)(hreg+0);  hp[1] = *(float4*)(hreg+4); } }

    int cur = 0;
    for (int t=0; t<T_SEQ; t++){
        // stage x_t for this block's 8 rows
        if (tid < 60){
            int k = tid >> 1, q = tid & 1;
            float4 v = *(const float4*)(xall + ((size_t)t*30 + k)*N_ROWS + n0 + q*4);
            *(float4*)(xs + k*8 + q*4) = v;
        }
        __syncthreads();
        int nxt = cur ^ 1;

        // ---- layer 1: z = [x_t, h1] @ W1 + b1
        #pragma unroll
        for (int r=0;r<8;r++){ accA[r]=b1v.x; accB[r]=b1v.y; }
        GK(pw1, xs,      0,  30);
        GK(pw1, h1[cur], 30, 100);
        EPI(cs1, h1[nxt]);
        __syncthreads();

        // ---- layer 2: z = [h1_new, h2] @ W2 + b2
        #pragma unroll
        for (int r=0;r<8;r++){ accA[r]=b2v.x; accB[r]=b2v.y; }
        GK(pw2, h1[nxt], 0,   100);
        GK(pw2, h2[cur], 100, 100);
        EPI(cs2, h2[nxt]);
        __syncthreads();

        // ---- fused 1x1 projection: out[n][t] = h2_new . we + be
        if (tid < 64){
            int r = tid & 7, s = tid >> 3;           // s in [0,8)
            int cb = s*13, ce = (s==7) ? 100 : cb+13;
            float pth = 0.f;
            for (int cc=cb; cc<ce; cc++)
                pth = fmaf(h2[nxt][cc*8 + r], we[cc], pth);
            pbuf[tid] = pth;
        }
        __syncthreads();
        if (tid < 8){
            float s = be[0];
            #pragma unroll
            for (int q=0;q<8;q++) s += pbuf[q*8 + tid];
            out[(size_t)(n0+tid)*T_SEQ + t] = s;
        }
        cur = nxt;
    }
#undef GK
#undef EPI
}

// ---------------------------------------------------------------------------
extern "C" void kernel_launch(void* const* d_in, const int* in_sizes, int n_in,
                              void* d_out, int out_size, void* d_ws, size_t ws_size,
                              hipStream_t stream)
{
    const float* x    = (const float*)d_in[0];
    const float* w10  = (const float*)d_in[1];  const float* b10 = (const float*)d_in[2];
    const float* w11  = (const float*)d_in[3];  const float* b11 = (const float*)d_in[4];
    const float* w12  = (const float*)d_in[5];  const float* b12 = (const float*)d_in[6];
    const float* w13  = (const float*)d_in[7];  const float* b13 = (const float*)d_in[8];
    const float* w20  = (const float*)d_in[9];  const float* b20 = (const float*)d_in[10];
    const float* w21  = (const float*)d_in[11]; const float* b21 = (const float*)d_in[12];
    const float* w22  = (const float*)d_in[13]; const float* b22 = (const float*)d_in[14];
    const float* w23  = (const float*)d_in[15]; const float* b23 = (const float*)d_in[16];
    const float* l1w  = (const float*)d_in[17]; const float* l1b = (const float*)d_in[18];
    const float* l2w  = (const float*)d_in[19]; const float* l2b = (const float*)d_in[20];
    const float* we   = (const float*)d_in[21]; const float* be  = (const float*)d_in[22];
    float* out = (float*)d_out;

    // workspace: conv slab 71.4 MB + packed weights ~0.7 MB
    const size_t NF = (size_t)30*N_ROWS;
    float* buf0 = (float*)d_ws;                    // [55][30][N]
    float* pw1  = buf0 + (size_t)T_SEQ*NF;         // [130][512]
    float* pw2  = pw1 + 130*512;                   // [200][512]
    float* pb1  = pw2 + 200*512;                   // [512]
    float* pb2  = pb1 + 512;                       // [512]

    repack_w2<<<(130*512+200*512+1024+255)/256, 256, 0, stream>>>(
        l1w, l1b, l2w, l2b, pw1, pb1, pw2, pb2);

    dim3 g1((N_ROWS+255)/256, T_SEQ);
    conv1x1_chain<<<g1, 256, 0, stream>>>(x, w10,b10, w11,b11, w12,b12, w13,b13, buf0);
    conv5x5<<<T_SEQ*64, 192, 0, stream>>>(buf0, w20, b20);
    conv5x5<<<T_SEQ*64, 192, 0, stream>>>(buf0, w21, b21);
    conv5x5<<<T_SEQ*64, 192, 0, stream>>>(buf0, w22, b22);
    conv5x5<<<T_SEQ*64, 192, 0, stream>>>(buf0, w23, b23);

    lstm_persist3<<<N_ROWS/8, 256, 0, stream>>>(buf0, pw1, pb1, pw2, pb2,
                                                we, be, out);
}

// Round 7
// 5069.912 us; speedup vs baseline: 1.1876x; 1.1876x over previous
//
#include <hip/hip_runtime.h>
#include <math.h>

#define N_ROWS 10816   // 64 * 169 rows per timestep
#define T_SEQ 55
#define NPIX 169

__device__ __forceinline__ float sigmoidf_(float x){ return 1.0f/(1.0f+expf(-x)); }

// ---------------------------------------------------------------------------
// Kernel 1: fused input transpose + 4x (1x1 conv + ReLU) chain. (unchanged)
// ---------------------------------------------------------------------------
__global__ __launch_bounds__(256) void conv1x1_chain(
    const float* __restrict__ x,
    const float* __restrict__ w0, const float* __restrict__ b0,
    const float* __restrict__ w1, const float* __restrict__ b1,
    const float* __restrict__ w2, const float* __restrict__ b2,
    const float* __restrict__ w3, const float* __restrict__ b3,
    float* __restrict__ out)
{
    int n = blockIdx.x*256 + threadIdx.x;
    int l = blockIdx.y;
    if (n >= N_ROWS) return;
    const float* xp = x + ((size_t)n*T_SEQ + l)*24;
    float in24[24];
    #pragma unroll
    for (int i=0;i<6;i++){
        float4 v = *(const float4*)(xp + 4*i);
        in24[4*i]=v.x; in24[4*i+1]=v.y; in24[4*i+2]=v.z; in24[4*i+3]=v.w;
    }
    float a[30], c[30];
    #pragma unroll
    for (int co=0;co<30;co++) a[co]=b0[co];
    #pragma unroll
    for (int ci=0;ci<24;ci++){
        float v = in24[ci];
        #pragma unroll
        for (int co=0;co<30;co++) a[co] = fmaf(v, w0[ci*30+co], a[co]);
    }
    #pragma unroll
    for (int co=0;co<30;co++) a[co] = fmaxf(a[co],0.f);

#define LAYER30(wp, bp) \
    { _Pragma("unroll") for (int co=0;co<30;co++) c[co]=(bp)[co]; \
      _Pragma("unroll") for (int ci=0;ci<30;ci++){ float v=a[ci]; \
        _Pragma("unroll") for (int co=0;co<30;co++) c[co]=fmaf(v,(wp)[ci*30+co],c[co]); } \
      _Pragma("unroll") for (int co=0;co<30;co++) a[co]=fmaxf(c[co],0.f); }

    LAYER30(w1,b1);
    LAYER30(w2,b2);
    LAYER30(w3,b3);
#undef LAYER30

    float* op = out + (size_t)l*30*N_ROWS + n;
    #pragma unroll
    for (int co=0;co<30;co++) op[(size_t)co*N_ROWS] = a[co];
}

// ---------------------------------------------------------------------------
// Kernel 2: 5x5 SAME conv + ReLU, channel-major, IN-PLACE, TWO-PHASE staging.
// (unchanged from R3)
// ---------------------------------------------------------------------------
__global__ __launch_bounds__(192) void conv5x5(
    float* __restrict__ buf, const float* __restrict__ w,
    const float* __restrict__ bias)
{
    __shared__ float img[15*289];
    int bi = blockIdx.x;
    int l = bi >> 6;
    int b = bi & 63;
    float* ip = buf + (size_t)l*30*N_ROWS + (size_t)b*NPIX;
    int tid = threadIdx.x;

    int p = tid;
    bool act = p < 169;
    int pc = act ? p : 0;
    int y = pc/13, x0 = pc - y*13;

    float acc[30];
    #pragma unroll
    for (int co=0;co<30;co++) acc[co]=bias[co];

    for (int i = tid; i < 15*289; i += 192) img[i] = 0.f;

    for (int half = 0; half < 2; half++){
        __syncthreads();
        for (int i = tid; i < 15*169; i += 192){
            int ci = i/169, pp = i - ci*169;
            int yy = pp/13, xx = pp - yy*13;
            img[ci*289 + (yy+2)*17 + (xx+2)] =
                ip[(size_t)(half*15 + ci)*N_ROWS + pp];
        }
        __syncthreads();
        for (int dy=0; dy<5; dy++){
          for (int dx=0; dx<5; dx++){
            const float* wp = w + (size_t)((dy*5+dx)*30 + half*15)*30;
            const float* im = img + (y+dy)*17 + (x0+dx);
            #pragma unroll
            for (int ci=0; ci<15; ci++){
              float v = im[ci*289];
              #pragma unroll
              for (int co=0;co<30;co++) acc[co] = fmaf(v, wp[ci*30+co], acc[co]);
            }
          }
        }
    }
    if (act){
      #pragma unroll
      for (int co=0;co<30;co++) ip[(size_t)co*N_ROWS + p] = fmaxf(acc[co],0.f);
    }
}

// ---------------------------------------------------------------------------
// Kernel 3: weight repack. pc = c*4 + g (c zero-padded to 128), [k][512].
// (unchanged: a wave reading pc = lane*4 and 256+lane*4 gets two fully
// coalesced 1024 B float4 streams per k)
// ---------------------------------------------------------------------------
__global__ __launch_bounds__(256) void repack_w2(
    const float* __restrict__ l1w, const float* __restrict__ l1b,
    const float* __restrict__ l2w, const float* __restrict__ l2b,
    float* __restrict__ pw1, float* __restrict__ pb1,
    float* __restrict__ pw2, float* __restrict__ pb2)
{
    const int T1 = 130*512, T2 = 200*512;
    int i = blockIdx.x*256 + threadIdx.x;
    if (i < T1){
        int k = i >> 9, pc = i & 511, c = pc >> 2, g = pc & 3;
        pw1[i] = (c < 100) ? l1w[(size_t)k*400 + g*100 + c] : 0.f;
    } else if (i < T1 + T2){
        int ii = i - T1;
        int k = ii >> 9, pc = ii & 511, c = pc >> 2, g = pc & 3;
        pw2[ii] = (c < 100) ? l2w[(size_t)k*400 + g*100 + c] : 0.f;
    } else if (i < T1 + T2 + 512){
        int pc = i - T1 - T2, c = pc >> 2, g = pc & 3;
        pb1[pc] = (c < 100) ? l1b[g*100 + c] : 0.f;
    } else if (i < T1 + T2 + 1024){
        int pc = i - T1 - T2 - 512, c = pc >> 2, g = pc & 3;
        pb2[pc] = (c < 100) ? l2b[g*100 + c] : 0.f;
    }
}

// ---------------------------------------------------------------------------
// Kernel 4: PERSISTENT fused 2-layer LSTM + projection, v4.
// R5/R6 were LDS-read-pipe-bound (~14K broadcast ds_read_b128 /CU/step).
// Fix: lane owns 8 packed cols = 2 FULL cells (all 4 gates in-lane, no
// shfl); wave owns all 512 cols x 4 rows. Per wave-k: 2 coalesced float4
// weight loads + ONE broadcast ds_read_b128 + 32 FMA -> LDS reads/CU/step
// drop 3.5x, now below the VALU floor. h buffers [100][20] (pad 4: 16B-
// aligned rows, 8-bank spread on strided h-writes). Block = 4 waves x 16
// rows; grid 676.
// ---------------------------------------------------------------------------
#define HP 20   // padded row length for h/x LDS tiles
__global__ __launch_bounds__(256) void lstm_persist4(
    const float* __restrict__ xall,   // [55][30][N]
    const float* __restrict__ pw1, const float* __restrict__ pb1,
    const float* __restrict__ pw2, const float* __restrict__ pb2,
    const float* __restrict__ we,  const float* __restrict__ be,
    float* __restrict__ out)          // [N][55]
{
    __shared__ float xs[30*HP];       // [k][r pad]
    __shared__ float h1[2][100*HP];   // [c][r pad] double buffer
    __shared__ float h2[2][100*HP];
    __shared__ float pbuf[128];

    const int tid  = threadIdx.x;
    const int wave = tid >> 6;        // wave owns rows [wave*4, wave*4+4)
    const int lane = tid & 63;
    const int n0   = blockIdx.x * 16;
    const int r0   = wave * 4;
    const int cA   = lane;            // cell A (always < 100)
    const int cB   = 64 + lane;       // cell B (valid if lane < 36)
    const bool bval = (lane < 36);

    for (int i=tid; i<100*HP; i+=256){ h1[0][i]=0.f; h2[0][i]=0.f; }

    // cs[layer][cell(A/B)][row]
    float csA1[4]={0,0,0,0}, csB1[4]={0,0,0,0};
    float csA2[4]={0,0,0,0}, csB2[4]={0,0,0,0};

    const float4 b1A = *(const float4*)(pb1 + lane*4);
    const float4 b1B = *(const float4*)(pb1 + 256 + lane*4);
    const float4 b2A = *(const float4*)(pb2 + lane*4);
    const float4 b2B = *(const float4*)(pb2 + 256 + lane*4);

    __syncthreads();

    // acc[gate][row] for cells A and B
    float aA[4][4], aB[4][4];

#define GK(PW, ACT, KBASE, KLEN) \
    { _Pragma("unroll 2") \
      for (int k=0; k<(KLEN); k++){ \
        const float* wr = (PW) + (size_t)((KBASE)+k)*512 + lane*4; \
        float4 wA = *(const float4*)(wr); \
        float4 wB = *(const float4*)(wr + 256); \
        float4 av = *(const float4*)((ACT) + k*HP + r0); \
        const float avv[4] = {av.x, av.y, av.z, av.w}; \
        _Pragma("unroll") \
        for (int r=0;r<4;r++){ \
            aA[0][r]=fmaf(avv[r],wA.x,aA[0][r]); \
            aA[1][r]=fmaf(avv[r],wA.y,aA[1][r]); \
            aA[2][r]=fmaf(avv[r],wA.z,aA[2][r]); \
            aA[3][r]=fmaf(avv[r],wA.w,aA[3][r]); \
            aB[0][r]=fmaf(avv[r],wB.x,aB[0][r]); \
            aB[1][r]=fmaf(avv[r],wB.y,aB[1][r]); \
            aB[2][r]=fmaf(avv[r],wB.z,aB[2][r]); \
            aB[3][r]=fmaf(avv[r],wB.w,aB[3][r]); } } }

#define INITACC(BA, BB) \
    { _Pragma("unroll") \
      for (int r=0;r<4;r++){ \
        aA[0][r]=(BA).x; aA[1][r]=(BA).y; aA[2][r]=(BA).z; aA[3][r]=(BA).w; \
        aB[0][r]=(BB).x; aB[1][r]=(BB).y; aB[2][r]=(BB).z; aB[3][r]=(BB).w; } }

#define EPI(CSA, CSB, HDST) \
    { float hrA[4], hrB[4]; \
      _Pragma("unroll") \
      for (int r=0;r<4;r++){ \
        float gi = sigmoidf_(aA[0][r]); \
        float gj = tanhf(aA[1][r]); \
        float gf = sigmoidf_(aA[2][r] + 1.0f); \
        float go = sigmoidf_(aA[3][r]); \
        float cn = gf*(CSA)[r] + gi*gj; \
        (CSA)[r] = cn; hrA[r] = go * tanhf(cn); \
        gi = sigmoidf_(aB[0][r]); \
        gj = tanhf(aB[1][r]); \
        gf = sigmoidf_(aB[2][r] + 1.0f); \
        go = sigmoidf_(aB[3][r]); \
        cn = gf*(CSB)[r] + gi*gj; \
        (CSB)[r] = cn; hrB[r] = go * tanhf(cn); } \
      *(float4*)((HDST) + cA*HP + r0) = *(float4*)hrA; \
      if (bval) *(float4*)((HDST) + cB*HP + r0) = *(float4*)hrB; }

    int cur = 0;
    for (int t=0; t<T_SEQ; t++){
        // stage x_t for this block's 16 rows (full 64B-line fetches)
        if (tid < 120){
            int k = tid >> 2, q = tid & 3;
            float4 v = *(const float4*)(xall + ((size_t)t*30 + k)*N_ROWS + n0 + q*4);
            *(float4*)(xs + k*HP + q*4) = v;
        }
        __syncthreads();
        int nxt = cur ^ 1;

        // ---- layer 1: z = [x_t, h1] @ W1 + b1
        INITACC(b1A, b1B);
        GK(pw1, xs,      0,  30);
        GK(pw1, h1[cur], 30, 100);
        EPI(csA1, csB1, h1[nxt]);
        __syncthreads();

        // ---- layer 2: z = [h1_new, h2] @ W2 + b2
        INITACC(b2A, b2B);
        GK(pw2, h1[nxt], 0,   100);
        GK(pw2, h2[cur], 100, 100);
        EPI(csA2, csB2, h2[nxt]);
        __syncthreads();

        // ---- fused 1x1 projection: out[n][t] = h2_new . we + be
        if (tid < 128){
            int r = tid & 15, s = tid >> 4;          // s in [0,8)
            int cb = s*13, ce = (s==7) ? 100 : cb+13;
            float pth = 0.f;
            for (int cc=cb; cc<ce; cc++)
                pth = fmaf(h2[nxt][cc*HP + r], we[cc], pth);
            pbuf[tid] = pth;
        }
        __syncthreads();
        if (tid < 16){
            float s = be[0];
            #pragma unroll
            for (int q=0;q<8;q++) s += pbuf[q*16 + tid];
            out[(size_t)(n0+tid)*T_SEQ + t] = s;
        }
        cur = nxt;
    }
#undef GK
#undef INITACC
#undef EPI
}

// ---------------------------------------------------------------------------
extern "C" void kernel_launch(void* const* d_in, const int* in_sizes, int n_in,
                              void* d_out, int out_size, void* d_ws, size_t ws_size,
                              hipStream_t stream)
{
    const float* x    = (const float*)d_in[0];
    const float* w10  = (const float*)d_in[1];  const float* b10 = (const float*)d_in[2];
    const float* w11  = (const float*)d_in[3];  const float* b11 = (const float*)d_in[4];
    const float* w12  = (const float*)d_in[5];  const float* b12 = (const float*)d_in[6];
    const float* w13  = (const float*)d_in[7];  const float* b13 = (const float*)d_in[8];
    const float* w20  = (const float*)d_in[9];  const float* b20 = (const float*)d_in[10];
    const float* w21  = (const float*)d_in[11]; const float* b21 = (const float*)d_in[12];
    const float* w22  = (const float*)d_in[13]; const float* b22 = (const float*)d_in[14];
    const float* w23  = (const float*)d_in[15]; const float* b23 = (const float*)d_in[16];
    const float* l1w  = (const float*)d_in[17]; const float* l1b = (const float*)d_in[18];
    const float* l2w  = (const float*)d_in[19]; const float* l2b = (const float*)d_in[20];
    const float* we   = (const float*)d_in[21]; const float* be  = (const float*)d_in[22];
    float* out = (float*)d_out;

    // workspace: conv slab 71.4 MB + packed weights ~0.7 MB
    const size_t NF = (size_t)30*N_ROWS;
    float* buf0 = (float*)d_ws;                    // [55][30][N]
    float* pw1  = buf0 + (size_t)T_SEQ*NF;         // [130][512]
    float* pw2  = pw1 + 130*512;                   // [200][512]
    float* pb1  = pw2 + 200*512;                   // [512]
    float* pb2  = pb1 + 512;                       // [512]

    repack_w2<<<(130*512+200*512+1024+255)/256, 256, 0, stream>>>(
        l1w, l1b, l2w, l2b, pw1, pb1, pw2, pb2);

    dim3 g1((N_ROWS+255)/256, T_SEQ);
    conv1x1_chain<<<g1, 256, 0, stream>>>(x, w10,b10, w11,b11, w12,b12, w13,b13, buf0);
    conv5x5<<<T_SEQ*64, 192, 0, stream>>>(buf0, w20, b20);
    conv5x5<<<T_SEQ*64, 192, 0, stream>>>(buf0, w21, b21);
    conv5x5<<<T_SEQ*64, 192, 0, stream>>>(buf0, w22, b22);
    conv5x5<<<T_SEQ*64, 192, 0, stream>>>(buf0, w23, b23);

    lstm_persist4<<<N_ROWS/16, 256, 0, stream>>>(buf0, pw1, pb1, pw2, pb2,
                                                 we, be, out);
}